// Round 1
// 589.297 us; speedup vs baseline: 1.2599x; 1.2599x over previous
//
#include <hip/hip_runtime.h>
#include <math.h>

#define NB 32
#define NC 4
#define NH 512
#define NW 512
#define NT 64
#define NG 2
#define BK 32

typedef __attribute__((ext_vector_type(8))) short short8;
typedef __attribute__((ext_vector_type(4))) short short4v;
typedef __attribute__((ext_vector_type(4))) float float4v;

__device__ inline unsigned short f2bf(float f) {
  union { float f; unsigned u; } v; v.f = f;
  unsigned r = v.u + 0x7FFF + ((v.u >> 16) & 1);
  return (unsigned short)(r >> 16);
}

// async global->LDS, 16B per lane; dst is wave-uniform base, HW adds lane*16
__device__ __forceinline__ void gld16(const unsigned short* g, unsigned short* l) {
  __builtin_amdgcn_global_load_lds(
      (__attribute__((address_space(1))) const unsigned int*)g,
      (__attribute__((address_space(3))) unsigned int*)l, 16, 0, 0);
}

// ---------------------------------------------------------------------------
// Stage 1: per-h-chunk partials, float4 loads, no atomics.
// diffp[hc][bg][w], hc in [0,8)
// ---------------------------------------------------------------------------
__global__ __launch_bounds__(256) void k_diff(const float* __restrict__ xr,
                                              const float* __restrict__ xi,
                                              float* __restrict__ diffp) {
  int bg = blockIdx.x, hc = blockIdx.y;
  int b = bg >> 1, g = bg & 1;
  size_t c0 = ((size_t)(b * NC + 2 * g)) * NH * NW;
  size_t c1 = c0 + (size_t)NH * NW;
  int t = threadIdx.x;
  int q = t & 127, rg = t >> 7;
  int h0 = hc * 64;
  float4v acc = {0.f, 0.f, 0.f, 0.f};
  for (int r = rg; r < 64; r += 2) {
    size_t o = (size_t)(h0 + r) * NW + q * 4;
    float4v r0 = *(const float4v*)(xr + c0 + o);
    float4v i0 = *(const float4v*)(xi + c0 + o);
    float4v r1 = *(const float4v*)(xr + c1 + o);
    float4v i1 = *(const float4v*)(xi + c1 + o);
#pragma unroll
    for (int k = 0; k < 4; ++k)
      acc[k] += fabsf(fabsf(r0[k]) - fabsf(i1[k])) + fabsf(fabsf(r1[k]) - fabsf(i0[k]));
  }
  __shared__ float4v red[256];
  red[t] = acc;
  __syncthreads();
  if (t < 128) {
    float4v v = red[t];
    float4v u = red[t + 128];
#pragma unroll
    for (int k = 0; k < 4; ++k) v[k] += u[k];
    *(float4v*)(diffp + ((size_t)hc * 64 + bg) * NW + q * 4) = v;
  }
}

// ---------------------------------------------------------------------------
// Stage 2: sum 8 partials, T smallest per (b,g), stable-argsort rank.
// ---------------------------------------------------------------------------
__global__ void k_select(const float* __restrict__ diffp, int* __restrict__ sel) {
  __shared__ float v[NW];
  int w = threadIdx.x;
  int bg = blockIdx.x;
  float mine = 0.f;
#pragma unroll
  for (int hc = 0; hc < 8; ++hc) mine += diffp[((size_t)hc * 64 + bg) * NW + w];
  v[w] = mine;
  __syncthreads();
  int rank = 0;
  for (int u = 0; u < NW; ++u) {
    float o = v[u];
    rank += (o < mine) || (o == mine && u < w);
  }
  if (rank < NT) sel[bg * NT + rank] = w;
}

// ---------------------------------------------------------------------------
// Build A_big via LDS cos/sin LUT (identical quantized angles -> bit-identical)
// ---------------------------------------------------------------------------
__global__ __launch_bounds__(256) void k_build_T(unsigned short* __restrict__ Tb) {
  __shared__ float2 lt[512];
  int t = threadIdx.x;
  {
    float s, c;
    sincosf(6.2831853071795864769f * (float)t * (1.0f / 512.0f), &s, &c);
    lt[t] = make_float2(c, s);
    sincosf(6.2831853071795864769f * (float)(t + 256) * (1.0f / 512.0f), &s, &c);
    lt[t + 256] = make_float2(c, s);
  }
  __syncthreads();
#pragma unroll
  for (int i = 0; i < 4; ++i) {
    int idx = blockIdx.x * 1024 + i * 256 + t;
    int m = idx >> 10, k = idx & 1023;
    int hm = m & 511, rm = m >> 9;
    int hk = k & 511, rk = k >> 9;
    float2 cs = lt[(hm * hk) & 511];
    float val = (rm == rk) ? cs.x : (rk ? -cs.y : cs.y);
    Tb[idx] = f2bf(val * (1.0f / 512.0f));
  }
}

// ---------------------------------------------------------------------------
// Gather: coalesced row streaming + LDS transpose. Block = (img, 128-row chunk)
// Xg layout [n=img*64+j][k=ri*512+h] bf16
// ---------------------------------------------------------------------------
__global__ __launch_bounds__(256) void k_gather(const float* __restrict__ xr,
                                                const float* __restrict__ xi,
                                                const int* __restrict__ sel,
                                                unsigned short* __restrict__ Xg) {
  __shared__ short jmap[512];
  __shared__ __align__(16) unsigned short tile[2][64][136];
  int img = blockIdx.x, hc = blockIdx.y;
  int t = threadIdx.x;
  int b = img >> 2, g = (img >> 1) & 1;
  jmap[t] = -1;
  jmap[t + 256] = -1;
  __syncthreads();
  if (t < NT) {
    int w = sel[(b * NG + g) * NT + t];
    jmap[w] = (short)t;
  }
  __syncthreads();
  size_t base = (size_t)img * NH * NW + (size_t)hc * 128 * NW;
  for (int i = 0; i < 64; ++i) {
    int lin = i * 256 + t;                 // 0..16383
    int r = lin >> 7, q = lin & 127;
    size_t o = base + (size_t)r * NW + q * 4;
    float4v vr = *(const float4v*)(xr + o);
    float4v vi = *(const float4v*)(xi + o);
    short4v jm = *(const short4v*)&jmap[q * 4];
#pragma unroll
    for (int k = 0; k < 4; ++k) {
      int j = jm[k];
      if (j >= 0) {
        tile[0][j][r] = f2bf(vr[k]);
        tile[1][j][r] = f2bf(vi[k]);
      }
    }
  }
  __syncthreads();
  int j = t >> 2, s4 = t & 3;
  size_t orow = ((size_t)img * 64 + j) * 1024 + (size_t)hc * 128;
#pragma unroll
  for (int v = 0; v < 4; ++v) {
    int hl = v * 32 + s4 * 8;
    *(short8*)(Xg + orow + hl)       = *(const short8*)&tile[0][j][hl];
    *(short8*)(Xg + orow + 512 + hl) = *(const short8*)&tile[1][j][hl];
  }
}

// ---------------------------------------------------------------------------
// Build E via LUT, high-occupancy grid (64 bg x 16 chunks)
// ---------------------------------------------------------------------------
__global__ __launch_bounds__(256) void k_build_E(const int* __restrict__ sel,
                                                 unsigned short* __restrict__ Eb) {
  __shared__ int wsel[NT];
  __shared__ float2 lt[512];
  int bg = blockIdx.x;
  int t = threadIdx.x;
  {
    float s, c;
    sincosf(6.2831853071795864769f * (float)t * (1.0f / 512.0f), &s, &c);
    lt[t] = make_float2(c, s);
    sincosf(6.2831853071795864769f * (float)(t + 256) * (1.0f / 512.0f), &s, &c);
    lt[t + 256] = make_float2(c, s);
  }
  if (t < NT) wsel[t] = sel[bg * NT + t];
  __syncthreads();
  int base = blockIdx.y * 8192;
#pragma unroll
  for (int i = 0; i < 32; ++i) {
    int idx = base + i * 256 + t;           // 0 .. 131071
    int n = idx >> 7, kidx = idx & 127;
    int j = kidx & 63, half = kidx >> 6;
    int part = n >> 9, kk = n & 511;
    int w = wsel[j];
    float2 cs = lt[(kk * w) & 511];
    float val = part == 0 ? (half ? cs.y : cs.x) : (half ? cs.x : -cs.y);
    Eb[(size_t)bg * 131072 + idx] = f2bf(val);
  }
}

// ---------------------------------------------------------------------------
// GEMM stage 3: C[1024 x 8192] = T[1024 x 1024] * Xg^T. m97 structure:
// global_load_lds width 16, linear LDS [128][32], XOR k-quad swizzle
// (pre-swizzled global src + swizzled ds_read; 8-way conflict -> 2-way).
// ---------------------------------------------------------------------------
__global__ __launch_bounds__(256) void k_gemm3(const unsigned short* __restrict__ Tb,
                                               const unsigned short* __restrict__ Xg,
                                               unsigned short* __restrict__ Yg) {
  __shared__ __align__(16) unsigned short Al[128 * BK];
  __shared__ __align__(16) unsigned short Bl[128 * BK];
  int n0 = blockIdx.x * 128;
  int m0 = blockIdx.y * 128;
  int tid = threadIdx.x;
  int lane = tid & 63, wid = tid >> 6;
  int wm = wid >> 1, wn = wid & 1;
  int quad = lane >> 4, l15 = lane & 15;
  int srow = lane >> 2, sqd = lane & 3;

  float4v acc[4][4];
#pragma unroll
  for (int i = 0; i < 4; ++i)
#pragma unroll
    for (int j = 0; j < 4; ++j) acc[i][j] = (float4v){0.f, 0.f, 0.f, 0.f};

  for (int k0 = 0; k0 < 1024; k0 += BK) {
    __syncthreads();
#pragma unroll
    for (int p = 0; p < 2; ++p) {
      int chunk = wid * 2 + p;
      int row = chunk * 16 + srow;
      int sq = sqd ^ ((row >> 1) & 3);
      gld16(&Tb[(size_t)(m0 + row) * 1024 + k0 + sq * 8], &Al[chunk * 512]);
      gld16(&Xg[(size_t)(n0 + row) * 1024 + k0 + sq * 8], &Bl[chunk * 512]);
    }
    __syncthreads();

    short8 af[4], bfv[4];
#pragma unroll
    for (int tt = 0; tt < 4; ++tt) {
      int ra = wm * 64 + tt * 16 + l15;
      int rb = wn * 64 + tt * 16 + l15;
      af[tt]  = *(const short8*)&Al[ra * BK + ((quad ^ ((ra >> 1) & 3)) << 3)];
      bfv[tt] = *(const short8*)&Bl[rb * BK + ((quad ^ ((rb >> 1) & 3)) << 3)];
    }
#pragma unroll
    for (int tm = 0; tm < 4; ++tm)
#pragma unroll
      for (int tn = 0; tn < 4; ++tn)
        acc[tm][tn] = __builtin_amdgcn_mfma_f32_16x16x32_bf16(af[tm], bfv[tn], acc[tm][tn], 0, 0, 0);
  }

  // epilogue: C[m,n] -> Yg[(n>>6)][m&511][(m>>9)*64 + (n&63)]
#pragma unroll
  for (int tm = 0; tm < 4; ++tm)
#pragma unroll
    for (int tn = 0; tn < 4; ++tn)
#pragma unroll
      for (int r = 0; r < 4; ++r) {
        int m = m0 + wm * 64 + tm * 16 + quad * 4 + r;
        int n = n0 + wn * 64 + tn * 16 + l15;
        int img = n >> 6, j = n & 63;
        int h = m & 511, ri = m >> 9;
        Yg[((size_t)img * 512 + h) * 128 + ri * 64 + j] = f2bf(acc[tm][tn][r]);
      }
}

// ---------------------------------------------------------------------------
// GEMM stage 4 (batched over bg): same glds+swizzle structure, K=128.
// ---------------------------------------------------------------------------
__global__ __launch_bounds__(256) void k_gemm4(const unsigned short* __restrict__ Yg,
                                               const unsigned short* __restrict__ Eball,
                                               float2* __restrict__ out) {
  __shared__ __align__(16) unsigned short Al[128 * BK];
  __shared__ __align__(16) unsigned short Bl[128 * BK];
  int n0 = blockIdx.x * 64;          // kk base (64 kk -> 128 cols)
  int m0 = blockIdx.y * 128;
  int bg = blockIdx.z;
  int b = bg >> 1, g = bg & 1;
  int img0 = b * 4 + 2 * g;
  const unsigned short* Ab = Yg + (size_t)img0 * 512 * 128;
  const unsigned short* Eb = Eball + (size_t)bg * 131072;

  int tid = threadIdx.x;
  int lane = tid & 63, wid = tid >> 6;
  int wm = wid >> 1, wn = wid & 1;
  int quad = lane >> 4, l15 = lane & 15;
  int srow = lane >> 2, sqd = lane & 3;

  float4v acc[4][4];
#pragma unroll
  for (int i = 0; i < 4; ++i)
#pragma unroll
    for (int j = 0; j < 4; ++j) acc[i][j] = (float4v){0.f, 0.f, 0.f, 0.f};

  for (int k0 = 0; k0 < 128; k0 += BK) {
    __syncthreads();
#pragma unroll
    for (int p = 0; p < 2; ++p) {
      int chunk = wid * 2 + p;
      int row = chunk * 16 + srow;
      int sq = sqd ^ ((row >> 1) & 3);
      gld16(&Ab[(size_t)(m0 + row) * 128 + k0 + sq * 8], &Al[chunk * 512]);
      int l = row & 63, wnB = row >> 6;
      int part = l >> 5;
      int grow = part * 512 + n0 + wnB * 32 + (l & 31);
      gld16(&Eb[(size_t)grow * 128 + k0 + sq * 8], &Bl[chunk * 512]);
    }
    __syncthreads();

    short8 af[4], bfv[4];
#pragma unroll
    for (int tt = 0; tt < 4; ++tt) {
      int ra = wm * 64 + tt * 16 + l15;
      int rb = wn * 64 + tt * 16 + l15;
      af[tt]  = *(const short8*)&Al[ra * BK + ((quad ^ ((ra >> 1) & 3)) << 3)];
      bfv[tt] = *(const short8*)&Bl[rb * BK + ((quad ^ ((rb >> 1) & 3)) << 3)];
    }
#pragma unroll
    for (int tm = 0; tm < 4; ++tm)
#pragma unroll
      for (int tn = 0; tn < 4; ++tn)
        acc[tm][tn] = __builtin_amdgcn_mfma_f32_16x16x32_bf16(af[tm], bfv[tn], acc[tm][tn], 0, 0, 0);
  }

  // epilogue: pair real (t2) with imag (t2+2) -> float2 store
#pragma unroll
  for (int tm = 0; tm < 4; ++tm)
#pragma unroll
    for (int t2 = 0; t2 < 2; ++t2)
#pragma unroll
      for (int r = 0; r < 4; ++r) {
        int m = m0 + wm * 64 + tm * 16 + quad * 4 + r;
        int ch = m >> 9, h = m & 511;
        int img = img0 + ch;
        int kk = n0 + wn * 32 + t2 * 16 + l15;
        float2 v = make_float2(acc[tm][t2][r] + 0.5f, acc[tm][t2 + 2][r]);
        out[((size_t)(img * 512 + h)) * 512 + kk] = v;
      }
}

extern "C" void kernel_launch(void* const* d_in, const int* in_sizes, int n_in,
                              void* d_out, int out_size, void* d_ws, size_t ws_size,
                              hipStream_t stream) {
  const float* xr = (const float*)d_in[0];
  const float* xi = (const float*)d_in[1];
  float2* out = (float2*)d_out;

  char* ws = (char*)d_ws;
  float*          diffp = (float*)ws;                          // 1 MB
  int*            sel   = (int*)(ws + 1048576);                // 16 KB
  unsigned short* Tb    = (unsigned short*)(ws + 2097152);     // 2 MB
  unsigned short* Xg    = (unsigned short*)(ws + 4194304);     // 16 MB
  unsigned short* Yg    = (unsigned short*)(ws + 20971520);    // 16 MB
  unsigned short* Eb    = (unsigned short*)(ws + 37748736);    // 16 MB

  k_diff   <<<dim3(NB * NG, 8), 256, 0, stream>>>(xr, xi, diffp);
  k_select <<<NB * NG,          NW, 0, stream>>>(diffp, sel);
  k_build_T<<<1024,             256, 0, stream>>>(Tb);
  k_gather <<<dim3(NB * NC, 4), 256, 0, stream>>>(xr, xi, sel, Xg);
  k_build_E<<<dim3(NB * NG, 16),256, 0, stream>>>(sel, Eb);
  k_gemm3  <<<dim3(64, 8),      256, 0, stream>>>(Tb, Xg, Yg);
  k_gemm4  <<<dim3(8, 8, 64),   256, 0, stream>>>(Yg, Eb, out);
}

// Round 2
// 580.014 us; speedup vs baseline: 1.2800x; 1.0160x over previous
//
#include <hip/hip_runtime.h>
#include <math.h>

#define NB 32
#define NC 4
#define NH 512
#define NW 512
#define NT 64
#define NG 2
#define BK 32

typedef __attribute__((ext_vector_type(8))) short short8;
typedef __attribute__((ext_vector_type(4))) short short4v;
typedef __attribute__((ext_vector_type(4))) float float4v;

__device__ inline unsigned short f2bf(float f) {
  union { float f; unsigned u; } v; v.f = f;
  unsigned r = v.u + 0x7FFF + ((v.u >> 16) & 1);
  return (unsigned short)(r >> 16);
}

// async global->LDS, 16B per lane; dst is wave-uniform base, HW adds lane*16
__device__ __forceinline__ void gld16(const unsigned short* g, unsigned short* l) {
  __builtin_amdgcn_global_load_lds(
      (__attribute__((address_space(1))) const unsigned int*)g,
      (__attribute__((address_space(3))) unsigned int*)l, 16, 0, 0);
}

// ---------------------------------------------------------------------------
// Stage 1: per-h-chunk partials, float4 loads, no atomics.
// diffp[hc][bg][w], hc in [0,8)
// ---------------------------------------------------------------------------
__global__ __launch_bounds__(256) void k_diff(const float* __restrict__ xr,
                                              const float* __restrict__ xi,
                                              float* __restrict__ diffp) {
  int bg = blockIdx.x, hc = blockIdx.y;
  int b = bg >> 1, g = bg & 1;
  size_t c0 = ((size_t)(b * NC + 2 * g)) * NH * NW;
  size_t c1 = c0 + (size_t)NH * NW;
  int t = threadIdx.x;
  int q = t & 127, rg = t >> 7;
  int h0 = hc * 64;
  float4v acc = {0.f, 0.f, 0.f, 0.f};
  for (int r = rg; r < 64; r += 2) {
    size_t o = (size_t)(h0 + r) * NW + q * 4;
    float4v r0 = *(const float4v*)(xr + c0 + o);
    float4v i0 = *(const float4v*)(xi + c0 + o);
    float4v r1 = *(const float4v*)(xr + c1 + o);
    float4v i1 = *(const float4v*)(xi + c1 + o);
#pragma unroll
    for (int k = 0; k < 4; ++k)
      acc[k] += fabsf(fabsf(r0[k]) - fabsf(i1[k])) + fabsf(fabsf(r1[k]) - fabsf(i0[k]));
  }
  __shared__ float4v red[256];
  red[t] = acc;
  __syncthreads();
  if (t < 128) {
    float4v v = red[t];
    float4v u = red[t + 128];
#pragma unroll
    for (int k = 0; k < 4; ++k) v[k] += u[k];
    *(float4v*)(diffp + ((size_t)hc * 64 + bg) * NW + q * 4) = v;
  }
}

// ---------------------------------------------------------------------------
// Stage 2: sum 8 partials, T smallest per (b,g), stable-argsort rank.
// ---------------------------------------------------------------------------
__global__ void k_select(const float* __restrict__ diffp, int* __restrict__ sel) {
  __shared__ float v[NW];
  int w = threadIdx.x;
  int bg = blockIdx.x;
  float mine = 0.f;
#pragma unroll
  for (int hc = 0; hc < 8; ++hc) mine += diffp[((size_t)hc * 64 + bg) * NW + w];
  v[w] = mine;
  __syncthreads();
  int rank = 0;
  for (int u = 0; u < NW; ++u) {
    float o = v[u];
    rank += (o < mine) || (o == mine && u < w);
  }
  if (rank < NT) sel[bg * NT + rank] = w;
}

// ---------------------------------------------------------------------------
// Build A_big via LDS cos/sin LUT (identical quantized angles -> bit-identical)
// ---------------------------------------------------------------------------
__global__ __launch_bounds__(256) void k_build_T(unsigned short* __restrict__ Tb) {
  __shared__ float2 lt[512];
  int t = threadIdx.x;
  {
    float s, c;
    sincosf(6.2831853071795864769f * (float)t * (1.0f / 512.0f), &s, &c);
    lt[t] = make_float2(c, s);
    sincosf(6.2831853071795864769f * (float)(t + 256) * (1.0f / 512.0f), &s, &c);
    lt[t + 256] = make_float2(c, s);
  }
  __syncthreads();
#pragma unroll
  for (int i = 0; i < 4; ++i) {
    int idx = blockIdx.x * 1024 + i * 256 + t;
    int m = idx >> 10, k = idx & 1023;
    int hm = m & 511, rm = m >> 9;
    int hk = k & 511, rk = k >> 9;
    float2 cs = lt[(hm * hk) & 511];
    float val = (rm == rk) ? cs.x : (rk ? -cs.y : cs.y);
    Tb[idx] = f2bf(val * (1.0f / 512.0f));
  }
}

// ---------------------------------------------------------------------------
// Gather: coalesced row streaming + LDS transpose. Block = (img, 128-row chunk)
// Xg layout [n=img*64+j][k=ri*512+h] bf16
// ---------------------------------------------------------------------------
__global__ __launch_bounds__(256) void k_gather(const float* __restrict__ xr,
                                                const float* __restrict__ xi,
                                                const int* __restrict__ sel,
                                                unsigned short* __restrict__ Xg) {
  __shared__ short jmap[512];
  __shared__ __align__(16) unsigned short tile[2][64][136];
  int img = blockIdx.x, hc = blockIdx.y;
  int t = threadIdx.x;
  int b = img >> 2, g = (img >> 1) & 1;
  jmap[t] = -1;
  jmap[t + 256] = -1;
  __syncthreads();
  if (t < NT) {
    int w = sel[(b * NG + g) * NT + t];
    jmap[w] = (short)t;
  }
  __syncthreads();
  size_t base = (size_t)img * NH * NW + (size_t)hc * 128 * NW;
  for (int i = 0; i < 64; ++i) {
    int lin = i * 256 + t;                 // 0..16383
    int r = lin >> 7, q = lin & 127;
    size_t o = base + (size_t)r * NW + q * 4;
    float4v vr = *(const float4v*)(xr + o);
    float4v vi = *(const float4v*)(xi + o);
    short4v jm = *(const short4v*)&jmap[q * 4];
#pragma unroll
    for (int k = 0; k < 4; ++k) {
      int j = jm[k];
      if (j >= 0) {
        tile[0][j][r] = f2bf(vr[k]);
        tile[1][j][r] = f2bf(vi[k]);
      }
    }
  }
  __syncthreads();
  int j = t >> 2, s4 = t & 3;
  size_t orow = ((size_t)img * 64 + j) * 1024 + (size_t)hc * 128;
#pragma unroll
  for (int v = 0; v < 4; ++v) {
    int hl = v * 32 + s4 * 8;
    *(short8*)(Xg + orow + hl)       = *(const short8*)&tile[0][j][hl];
    *(short8*)(Xg + orow + 512 + hl) = *(const short8*)&tile[1][j][hl];
  }
}

// ---------------------------------------------------------------------------
// Build E via LUT, high-occupancy grid (64 bg x 16 chunks)
// ---------------------------------------------------------------------------
__global__ __launch_bounds__(256) void k_build_E(const int* __restrict__ sel,
                                                 unsigned short* __restrict__ Eb) {
  __shared__ int wsel[NT];
  __shared__ float2 lt[512];
  int bg = blockIdx.x;
  int t = threadIdx.x;
  {
    float s, c;
    sincosf(6.2831853071795864769f * (float)t * (1.0f / 512.0f), &s, &c);
    lt[t] = make_float2(c, s);
    sincosf(6.2831853071795864769f * (float)(t + 256) * (1.0f / 512.0f), &s, &c);
    lt[t + 256] = make_float2(c, s);
  }
  if (t < NT) wsel[t] = sel[bg * NT + t];
  __syncthreads();
  int base = blockIdx.y * 8192;
#pragma unroll
  for (int i = 0; i < 32; ++i) {
    int idx = base + i * 256 + t;           // 0 .. 131071
    int n = idx >> 7, kidx = idx & 127;
    int j = kidx & 63, half = kidx >> 6;
    int part = n >> 9, kk = n & 511;
    int w = wsel[j];
    float2 cs = lt[(kk * w) & 511];
    float val = part == 0 ? (half ? cs.y : cs.x) : (half ? cs.x : -cs.y);
    Eb[(size_t)bg * 131072 + idx] = f2bf(val);
  }
}

// ---------------------------------------------------------------------------
// GEMM stage 3: C[1024 x 8192] = T[1024 x 1024] * Xg^T.
// Double-buffered LDS, prefetch-next-then-compute (T3-minimum), one barrier
// per K-step. XOR k-quad swizzle via pre-swizzled global src. XCD swizzle.
// ---------------------------------------------------------------------------
__global__ __launch_bounds__(256) void k_gemm3(const unsigned short* __restrict__ Tb,
                                               const unsigned short* __restrict__ Xg,
                                               unsigned short* __restrict__ Yg) {
  __shared__ __align__(16) unsigned short Al[2][128 * BK];
  __shared__ __align__(16) unsigned short Bl[2][128 * BK];
  // bijective chunked XCD swizzle, nwg = 512
  int lin = blockIdx.y * 64 + blockIdx.x;
  int swz = (lin & 7) * 64 + (lin >> 3);
  int n0 = (swz & 63) * 128;
  int m0 = (swz >> 6) * 128;
  int tid = threadIdx.x;
  int lane = tid & 63, wid = tid >> 6;
  int wm = wid >> 1, wn = wid & 1;
  int quad = lane >> 4, l15 = lane & 15;
  int srow = lane >> 2, sqd = lane & 3;

  float4v acc[4][4];
#pragma unroll
  for (int i = 0; i < 4; ++i)
#pragma unroll
    for (int j = 0; j < 4; ++j) acc[i][j] = (float4v){0.f, 0.f, 0.f, 0.f};

#define STAGE3(buf, kk0)                                                        \
  {                                                                             \
    _Pragma("unroll")                                                           \
    for (int p = 0; p < 2; ++p) {                                               \
      int chunk = wid * 2 + p;                                                  \
      int row = chunk * 16 + srow;                                              \
      int sq = sqd ^ ((row >> 1) & 3);                                          \
      gld16(&Tb[(size_t)(m0 + row) * 1024 + (kk0) + sq * 8], &Al[buf][chunk * 512]); \
      gld16(&Xg[(size_t)(n0 + row) * 1024 + (kk0) + sq * 8], &Bl[buf][chunk * 512]); \
    }                                                                           \
  }

  STAGE3(0, 0);
  __syncthreads();
  int cur = 0;
  for (int t = 0; t < 32; ++t) {
    if (t < 31) STAGE3(cur ^ 1, (t + 1) * 32);

    short8 af[4], bfv[4];
#pragma unroll
    for (int tt = 0; tt < 4; ++tt) {
      int ra = wm * 64 + tt * 16 + l15;
      int rb = wn * 64 + tt * 16 + l15;
      af[tt]  = *(const short8*)&Al[cur][ra * BK + ((quad ^ ((ra >> 1) & 3)) << 3)];
      bfv[tt] = *(const short8*)&Bl[cur][rb * BK + ((quad ^ ((rb >> 1) & 3)) << 3)];
    }
#pragma unroll
    for (int tm = 0; tm < 4; ++tm)
#pragma unroll
      for (int tn = 0; tn < 4; ++tn)
        acc[tm][tn] = __builtin_amdgcn_mfma_f32_16x16x32_bf16(af[tm], bfv[tn], acc[tm][tn], 0, 0, 0);

    __syncthreads();
    cur ^= 1;
  }

  // epilogue: C[m,n] -> Yg[(n>>6)][m&511][(m>>9)*64 + (n&63)]
#pragma unroll
  for (int tm = 0; tm < 4; ++tm)
#pragma unroll
    for (int tn = 0; tn < 4; ++tn)
#pragma unroll
      for (int r = 0; r < 4; ++r) {
        int m = m0 + wm * 64 + tm * 16 + quad * 4 + r;
        int n = n0 + wn * 64 + tn * 16 + l15;
        int img = n >> 6, j = n & 63;
        int h = m & 511, ri = m >> 9;
        Yg[((size_t)img * 512 + h) * 128 + ri * 64 + j] = f2bf(acc[tm][tn][r]);
      }
}

// ---------------------------------------------------------------------------
// GEMM stage 4 (batched over bg): whole-K (128) single-stage LDS panel,
// one barrier pair, 64 MFMA/wave unbroken. LDS row stride 256 B would be a
// 16-way bank conflict -> chunk-XOR swizzle (src-preswizzled, read-swizzled).
// ---------------------------------------------------------------------------
__global__ __launch_bounds__(256) void k_gemm4(const unsigned short* __restrict__ Yg,
                                               const unsigned short* __restrict__ Eball,
                                               float2* __restrict__ out) {
  __shared__ __align__(16) unsigned short Al[128 * 128];
  __shared__ __align__(16) unsigned short Bl[128 * 128];
  // bijective chunked XCD swizzle, nwg = 4096 -> 8 bg per XCD (~4MB L2 set)
  int lin = blockIdx.x + blockIdx.y * 8 + blockIdx.z * 64;
  int swz = (lin & 7) * 512 + (lin >> 3);
  int n0 = (swz & 7) * 64;           // kk base (64 kk -> 128 cols)
  int m0 = ((swz >> 3) & 7) * 128;
  int bg = swz >> 6;
  int b = bg >> 1, g = bg & 1;
  int img0 = b * 4 + 2 * g;
  const unsigned short* Ab = Yg + (size_t)img0 * 512 * 128;
  const unsigned short* Eb = Eball + (size_t)bg * 131072;

  int tid = threadIdx.x;
  int lane = tid & 63, wid = tid >> 6;
  int wm = wid >> 1, wn = wid & 1;
  int quad = lane >> 4, l15 = lane & 15;
  int lrow4 = lane >> 4, cch = lane & 15;

  // stage whole 128x128 panels: 32 gld16 calls each, 8 per wave
#pragma unroll
  for (int c8 = 0; c8 < 8; ++c8) {
    int call = wid * 8 + c8;            // 0..31, wave-uniform
    int row = call * 4 + lrow4;         // LDS row this lane feeds
    int sch = cch ^ (row & 7);          // inverse swizzle on global src
    gld16(&Ab[(size_t)(m0 + row) * 128 + sch * 8], &Al[call * 512]);
    int l = row & 63, wnB = row >> 6;
    int part = l >> 5;
    int grow = part * 512 + n0 + wnB * 32 + (l & 31);
    gld16(&Eb[(size_t)grow * 128 + sch * 8], &Bl[call * 512]);
  }
  __syncthreads();

  float4v acc[4][4];
#pragma unroll
  for (int i = 0; i < 4; ++i)
#pragma unroll
    for (int j = 0; j < 4; ++j) acc[i][j] = (float4v){0.f, 0.f, 0.f, 0.f};

#pragma unroll
  for (int ks = 0; ks < 4; ++ks) {
    short8 af[4], bfv[4];
#pragma unroll
    for (int tt = 0; tt < 4; ++tt) {
      int ra = wm * 64 + tt * 16 + l15;
      int rb = wn * 64 + tt * 16 + l15;
      af[tt]  = *(const short8*)&Al[ra * 128 + (((ks * 4 + quad) ^ (ra & 7)) << 3)];
      bfv[tt] = *(const short8*)&Bl[rb * 128 + (((ks * 4 + quad) ^ (rb & 7)) << 3)];
    }
#pragma unroll
    for (int tm = 0; tm < 4; ++tm)
#pragma unroll
      for (int tn = 0; tn < 4; ++tn)
        acc[tm][tn] = __builtin_amdgcn_mfma_f32_16x16x32_bf16(af[tm], bfv[tn], acc[tm][tn], 0, 0, 0);
  }

  // epilogue: pair real (t2) with imag (t2+2) -> float2 store
#pragma unroll
  for (int tm = 0; tm < 4; ++tm)
#pragma unroll
    for (int t2 = 0; t2 < 2; ++t2)
#pragma unroll
      for (int r = 0; r < 4; ++r) {
        int m = m0 + wm * 64 + tm * 16 + quad * 4 + r;
        int ch = m >> 9, h = m & 511;
        int img = img0 + ch;
        int kk = n0 + wn * 32 + t2 * 16 + l15;
        float2 v = make_float2(acc[tm][t2][r] + 0.5f, acc[tm][t2 + 2][r]);
        out[((size_t)(img * 512 + h)) * 512 + kk] = v;
      }
}

extern "C" void kernel_launch(void* const* d_in, const int* in_sizes, int n_in,
                              void* d_out, int out_size, void* d_ws, size_t ws_size,
                              hipStream_t stream) {
  const float* xr = (const float*)d_in[0];
  const float* xi = (const float*)d_in[1];
  float2* out = (float2*)d_out;

  char* ws = (char*)d_ws;
  float*          diffp = (float*)ws;                          // 1 MB
  int*            sel   = (int*)(ws + 1048576);                // 16 KB
  unsigned short* Tb    = (unsigned short*)(ws + 2097152);     // 2 MB
  unsigned short* Xg    = (unsigned short*)(ws + 4194304);     // 16 MB
  unsigned short* Yg    = (unsigned short*)(ws + 20971520);    // 16 MB
  unsigned short* Eb    = (unsigned short*)(ws + 37748736);    // 16 MB

  k_diff   <<<dim3(NB * NG, 8), 256, 0, stream>>>(xr, xi, diffp);
  k_select <<<NB * NG,          NW, 0, stream>>>(diffp, sel);
  k_build_T<<<1024,             256, 0, stream>>>(Tb);
  k_gather <<<dim3(NB * NC, 4), 256, 0, stream>>>(xr, xi, sel, Xg);
  k_build_E<<<dim3(NB * NG, 16),256, 0, stream>>>(sel, Eb);
  k_gemm3  <<<dim3(64, 8),      256, 0, stream>>>(Tb, Xg, Yg);
  k_gemm4  <<<dim3(8, 8, 64),   256, 0, stream>>>(Yg, Eb, out);
}